// Round 3
// baseline (147.890 us; speedup 1.0000x reference)
//
#include <hip/hip_runtime.h>
#include <hip/hip_bf16.h>

typedef unsigned long long u64;

#define NB 16
#define HW 512
#define PIX_PER_B (HW * HW)            // 262144
#define NPIX (NB * PIX_PER_B)          // 4194304
#define WORDS_PER_B (PIX_PER_B / 64)   // 4096
#define SROW 9                         // LDS row stride in u64 (8 + 1 pad)

#define WS_PART_OFF 1024
#define WS_MASK_OFF 32768
#define WS_NEED_MASKS (WS_MASK_OFF + (size_t)2 * NB * WORDS_PER_B * 8)

#define RED_BLOCKS 224                 // reduce blocks inside fused kernel
#define FB_BLOCKS 512                  // fallback loss_reduce blocks

// ---------------- bit-sliced Zhang-Suen helpers ----------------

__device__ __forceinline__ void fa3(u64 a, u64 b, u64 c, u64& s, u64& cy) {
  u64 x = a ^ b;
  s = x ^ c;
  cy = (a & b) | (c & x);
}

__device__ __forceinline__ u64 thin_word(u64 nm, u64 nl, u64 nr,
                                         u64 cm, u64 cl, u64 cr,
                                         u64 sm, u64 sl, u64 sr, int sub) {
  u64 p2 = nm;                          // N
  u64 p3 = (nm >> 1) | (nr << 63);      // NE
  u64 p4 = (cm >> 1) | (cr << 63);      // E
  u64 p5 = (sm >> 1) | (sr << 63);      // SE
  u64 p6 = sm;                          // S
  u64 p7 = (sm << 1) | (sl >> 63);      // SW
  u64 p8 = (cm << 1) | (cl >> 63);      // W
  u64 p9 = (nm << 1) | (nl >> 63);      // NW

  u64 u1, v1, u2, v2, ss, sc, cs, cc;
  fa3(p2, p3, p4, u1, v1);
  fa3(p5, p6, p7, u2, v2);
  u64 u3 = p8 ^ p9, v3 = p8 & p9;
  fa3(u1, u2, u3, ss, sc);
  fa3(v1, v2, v3, cs, cc);
  u64 w  = sc & cs;
  u64 b1 = sc ^ cs;
  u64 b2 = cc ^ w;
  u64 b3 = cc & w;
  u64 cond1 = (sc | cs | cc) & ~(b3 | (b2 & b1 & ss));  // 2 <= B <= 6

  u64 t0 = ~p2 & p3, t1 = ~p3 & p4, t2 = ~p4 & p5, t3 = ~p5 & p6;
  u64 t4 = ~p6 & p7, t5 = ~p7 & p8, t6 = ~p8 & p9, t7 = ~p9 & p2;
  u64 as1, ac1, as2, ac2, Ass, Asc, Acs, Acc;
  fa3(t0, t1, t2, as1, ac1);
  fa3(t3, t4, t5, as2, ac2);
  u64 as3 = t6 ^ t7, ac3 = t6 & t7;
  fa3(as1, as2, as3, Ass, Asc);
  fa3(ac1, ac2, ac3, Acs, Acc);
  u64 cond2 = Ass & ~(Asc | Acs | Acc);  // A == 1

  u64 cond3, cond4;
  if (sub == 0) { cond3 = ~(p2 & p4 & p6); cond4 = ~(p4 & p6 & p8); }
  else          { cond3 = ~(p2 & p4 & p8); cond4 = ~(p2 & p6 & p8); }

  u64 rem = cm & cond1 & cond2 & cond3 & cond4;
  return cm & ~rem;
}

// ---------------- kernel 1: binarization masks only (no softmax needed:
// p1 > 0.5 <=> l1 > l0). Also zeroes clDice counters (block 0). ----------------

__global__ __launch_bounds__(256) void mask_kernel(
    const float* __restrict__ logits, const int* __restrict__ tr,
    unsigned char* __restrict__ ws) {
  int tid = threadIdx.x, blk = blockIdx.x;
  u64* predM = (u64*)(ws + WS_MASK_OFF);
  u64* trueM = predM + (size_t)NB * WORDS_PER_B;
  if (blk == 0 && tid < 56) ((u64*)(ws + 64))[tid] = 0;  // zero bytes [64,512)
#pragma unroll 4
  for (int it = 0; it < 64; ++it) {
    int g = (it * 256 + blk) * 256 + tid;
    int b = g >> 18;
    int r = g & (PIX_PER_B - 1);
    const float* lp = logits + (size_t)b * 2 * PIX_PER_B + r;
    float l0 = lp[0], l1 = lp[PIX_PER_B];
    int t = tr[g];
    u64 pm = __ballot(l1 > l0);
    u64 tm = __ballot(t > 0);
    if ((tid & 63) == 0) { predM[g >> 6] = pm; trueM[g >> 6] = tm; }
  }
}

// ---------------- kernel 2: FUSED. Blocks 0..31: skeletonize one image each.
// Blocks 32..255: dice/focal reduction (runs concurrently on idle CUs). ----------------

__global__ __launch_bounds__(1024) void fused_kernel(
    const float* __restrict__ logits, const int* __restrict__ tr,
    unsigned char* __restrict__ ws) {
  __shared__ u64 S[HW * SROW];                  // 36 KB (skel path)
  __shared__ unsigned char dirty[2][130];
  __shared__ int flag;
  __shared__ double red[16][6];                 // reduce path

  int tid  = threadIdx.x;
  int lane = tid & 63;

  if (blockIdx.x < 32) {
    // ------------- skeletonization path -------------
    int b    = blockIdx.x;                      // 0..31 (0..15 pred, 16..31 true)
    int img  = b & 15;
    int wcol = tid & 7;
    int s    = tid >> 3;                        // strip 0..127 (4 rows)
    int r0   = s * 4;

    u64* region = (u64*)(ws + WS_MASK_OFF) + (size_t)b * WORDS_PER_B;
    u64* clSp = (u64*)(ws + 192);
    u64* clSt = (u64*)(ws + 320);

#pragma unroll
    for (int i = 0; i < 4; i++)
      S[(r0 + i) * SROW + wcol] = region[(r0 + i) * 8 + wcol];
    if (tid < 130) {
      unsigned char init = (tid >= 1 && tid <= 128) ? 1 : 0;
      dirty[0][tid] = init;
      dirty[1][tid] = init;
    }
    if (tid == 0) flag = 0;
    __syncthreads();

    auto loadRow = [&](int r, u64& m, u64& l, u64& rr) {
      if (r < 0 || r >= HW) { m = 0; l = 0; rr = 0; return; }
      const u64* row = &S[r * SROW];
      m  = row[wcol];
      l  = wcol ? row[wcol - 1] : 0ULL;
      rr = (wcol < 7) ? row[wcol + 1] : 0ULL;
    };

    auto subIter = [&](int sub, int db, int pairTag) {
      unsigned char* dOut = dirty[db ^ 1];
      bool laneActive = (dirty[0][s] | dirty[0][s + 1] | dirty[0][s + 2] |
                         dirty[1][s] | dirty[1][s + 1] | dirty[1][s + 2]) != 0;
      u64 wmask = __ballot(laneActive);         // whole-wave skip (32-row band)
      bool stripCh = false;
      u64 nw[4];
      bool doit = (wmask != 0);
      if (doit) {
        u64 am, al, ar, bm, bl, br, cmv, clv, crv, oldc[4];
        loadRow(r0 - 1, am, al, ar);
        loadRow(r0,     bm, bl, br);
#pragma unroll
        for (int i = 0; i < 4; i++) {
          loadRow(r0 + 1 + i, cmv, clv, crv);
          oldc[i] = bm;
          nw[i] = thin_word(am, al, ar, bm, bl, br, cmv, clv, crv, sub);
          am = bm; al = bl; ar = br;
          bm = cmv; bl = clv; br = crv;
        }
        bool ch = false;
#pragma unroll
        for (int i = 0; i < 4; i++) ch |= (nw[i] != oldc[i]);
        u64 bal = __ballot(ch);
        stripCh = ((bal >> (lane & 56)) & 0xFFULL) != 0;
      }
      __syncthreads();                          // reads of old state done
      if (doit) {
#pragma unroll
        for (int i = 0; i < 4; i++) S[(r0 + i) * SROW + wcol] = nw[i];
      }
      if ((tid & 7) == 0) {
        dOut[s + 1] = stripCh ? 1 : 0;
        if (stripCh) flag = pairTag;            // benign same-value race
      }
      __syncthreads();                          // writes + dirty + flag visible
    };

    for (int pair = 1; pair <= 2000; ++pair) {
      subIter(0, 0, pair);
      subIter(1, 1, pair);
      if (flag != pair) break;
    }

    u64 cnt = 0;
#pragma unroll
    for (int i = 0; i < 4; i++) {
      u64 w = S[(r0 + i) * SROW + wcol];
      region[(r0 + i) * 8 + wcol] = w;          // skeleton out (overwrites mask)
      cnt += (u64)__popcll(w);
    }
    for (int o = 32; o; o >>= 1) cnt += __shfl_down(cnt, o, 64);
    if (lane == 0) atomicAdd((b < NB ? clSp : clSt) + img, cnt);

  } else {
    // ------------- dice/focal reduction path -------------
    int rb = blockIdx.x - 32;                   // 0..223
    double a0 = 0, a1 = 0, s0 = 0, s1 = 0, cnt = 0, fo = 0;
    for (int g = rb * 1024 + tid; g < NPIX; g += RED_BLOCKS * 1024) {
      int b = g >> 18;
      int r = g & (PIX_PER_B - 1);
      const float* lp = logits + (size_t)b * 2 * PIX_PER_B + r;
      float l0 = lp[0], l1 = lp[PIX_PER_B];
      int t = tr[g];
      float m = fmaxf(l0, l1);
      float e0 = expf(l0 - m), e1 = expf(l1 - m);
      float ssum = e0 + e1;
      float p0 = e0 / ssum, p1 = e1 / ssum;
      if (t) a1 += (double)p1; else a0 += (double)p0;
      s0 += (double)p0;
      s1 += (double)p1;
      cnt += (double)t;
      float lse = m + logf(ssum);
      float ce = lse - (t ? l1 : l0);
      float pt = t ? p1 : p0;
      float om = 1.0f - pt;
      fo += (double)(0.25f * om * om * ce);
    }
    double v[6] = {a0, a1, s0, s1, cnt, fo};
    int wv = tid >> 6;
#pragma unroll
    for (int j = 0; j < 6; j++) {
      double x = v[j];
      for (int o = 32; o; o >>= 1) x += __shfl_down(x, o, 64);
      if (lane == 0) red[wv][j] = x;
    }
    __syncthreads();
    if (tid < 6) {
      double t6 = 0;
      for (int w = 0; w < 16; w++) t6 += red[w][tid];
      double* part = (double*)(ws + WS_PART_OFF) + (size_t)rb * 6;
      part[tid] = t6;
    }
  }
}

// ---------------- kernel 3: intersection popcount ----------------

__global__ __launch_bounds__(256) void inter_kernel(unsigned char* __restrict__ ws) {
  int i = blockIdx.x;
  int tid = threadIdx.x;
  const u64* p = (const u64*)(ws + WS_MASK_OFF) + (size_t)i * WORDS_PER_B;
  const u64* t = p + (size_t)NB * WORDS_PER_B;
  u64 acc = 0;
  for (int w = tid; w < WORDS_PER_B; w += 256) acc += (u64)__popcll(p[w] & t[w]);
  for (int o = 32; o; o >>= 1) acc += __shfl_down(acc, o, 64);
  __shared__ u64 r[4];
  if ((tid & 63) == 0) r[tid >> 6] = acc;
  __syncthreads();
  if (tid == 0) {
    u64* clInter = (u64*)(ws + 64);
    clInter[i] = r[0] + r[1] + r[2] + r[3];
  }
}

// ---------------- kernel 4: finalize ----------------

__global__ __launch_bounds__(512) void finalize_kernel(unsigned char* __restrict__ ws,
                                                       float* __restrict__ out, int count) {
  int tid = threadIdx.x;
  const double* part = (const double*)(ws + WS_PART_OFF);
  double v[6] = {0, 0, 0, 0, 0, 0};
  if (tid < count) {
#pragma unroll
    for (int j = 0; j < 6; j++) v[j] = part[(size_t)tid * 6 + j];
  }
  __shared__ double red[8][6];
  int lane = tid & 63, wv = tid >> 6;
#pragma unroll
  for (int j = 0; j < 6; j++) {
    double x = v[j];
    for (int o = 32; o; o >>= 1) x += __shfl_down(x, o, 64);
    if (lane == 0) red[wv][j] = x;
  }
  __syncthreads();
  if (tid == 0) {
    double t[6] = {0, 0, 0, 0, 0, 0};
    for (int w = 0; w < 8; w++)
      for (int j = 0; j < 6; j++) t[j] += red[w][j];
    double a0 = t[0], a1 = t[1], s0 = t[2], s1 = t[3], cnt = t[4], fo = t[5];

    const double N = (double)NPIX;
    double cnt0 = N - cnt;
    double card0 = s0 + cnt0, card1 = s1 + cnt;
    double dice = 0.5 * ((2.0 * a0 + 1e-6) / (card0 + 1e-6) +
                         (2.0 * a1 + 1e-6) / (card1 + 1e-6));
    double diceL = 1.0 - dice;
    double focalL = fo / N;

    const u64* clInter = (const u64*)(ws + 64);
    const u64* clSp    = (const u64*)(ws + 192);
    const u64* clSt    = (const u64*)(ws + 320);
    double cs = 0;
    for (int b = 0; b < NB; b++) {
      double inter = (double)clInter[b];
      double den = (double)(clSp[b] + clSt[b]);
      cs += (2.0 * inter + 1e-6) / (den + 1e-6);
    }
    double clL = 1.0 - cs / (double)NB;

    out[0] = (float)(0.7 * clL + 0.1 * diceL + 0.2 * focalL);
  }
}

// ---------------- fallback kernels (ws too small; not used when ws >= ~2 MB) ----------------

__global__ __launch_bounds__(256) void loss_reduce_fb_kernel(
    const float* __restrict__ logits, const int* __restrict__ tr,
    unsigned char* __restrict__ ws) {
  int tid = threadIdx.x;
  double a0 = 0, a1 = 0, s0 = 0, s1 = 0, cnt = 0, fo = 0;
  const int iters = NPIX / (FB_BLOCKS * 256);
  for (int it = 0; it < iters; ++it) {
    int g = (it * FB_BLOCKS + (int)blockIdx.x) * 256 + tid;
    int b = g >> 18;
    int r = g & (PIX_PER_B - 1);
    const float* lp = logits + (size_t)b * 2 * PIX_PER_B + r;
    float l0 = lp[0], l1 = lp[PIX_PER_B];
    int t = tr[g];
    float m = fmaxf(l0, l1);
    float e0 = expf(l0 - m), e1 = expf(l1 - m);
    float s = e0 + e1;
    float p0 = e0 / s, p1 = e1 / s;
    if (t) a1 += (double)p1; else a0 += (double)p0;
    s0 += (double)p0;
    s1 += (double)p1;
    cnt += (double)t;
    float lse = m + logf(s);
    float ce = lse - (t ? l1 : l0);
    float pt = t ? p1 : p0;
    float om = 1.0f - pt;
    fo += (double)(0.25f * om * om * ce);
  }
  __shared__ double red[4][6];
  double v[6] = {a0, a1, s0, s1, cnt, fo};
  int lane = tid & 63, wv = tid >> 6;
#pragma unroll
  for (int j = 0; j < 6; j++) {
    double x = v[j];
    for (int o = 32; o; o >>= 1) x += __shfl_down(x, o, 64);
    if (lane == 0) red[wv][j] = x;
  }
  __syncthreads();
  if (tid < 6) {
    double* part = (double*)(ws + WS_PART_OFF) + (size_t)blockIdx.x * 6;
    part[tid] = red[0][tid] + red[1][tid] + red[2][tid] + red[3][tid];
  }
}

__global__ __launch_bounds__(1024) void skel_combined_kernel(
    const float* __restrict__ logits, const int* __restrict__ tr,
    unsigned char* __restrict__ ws) {
  __shared__ u64 S[HW * SROW];
  __shared__ int flag;

  int tid  = threadIdx.x;
  int b    = blockIdx.x;
  int wcol = tid & 7;
  int r0   = (tid >> 3) * 4;
  int lane = tid & 63;

  u64* clInter = (u64*)(ws + 64);
  u64* clSp    = (u64*)(ws + 192);
  u64* clSt    = (u64*)(ws + 320);

  auto buildPred = [&]() {
    const float* lp0 = logits + (size_t)b * 2 * PIX_PER_B;
    const float* lp1 = lp0 + PIX_PER_B;
    for (int k = 0; k < PIX_PER_B / 1024; k++) {
      int p = k * 1024 + tid;
      u64 msk = __ballot(lp1[p] > lp0[p]);
      if (lane == 0) { int wi = p >> 6; S[(wi >> 3) * SROW + (wi & 7)] = msk; }
    }
    __syncthreads();
  };
  auto buildTrue = [&]() {
    const int* tp = tr + (size_t)b * PIX_PER_B;
    for (int k = 0; k < PIX_PER_B / 1024; k++) {
      int p = k * 1024 + tid;
      u64 msk = __ballot(tp[p] > 0);
      if (lane == 0) { int wi = p >> 6; S[(wi >> 3) * SROW + (wi & 7)] = msk; }
    }
    __syncthreads();
  };

  auto loadRow = [&](int r, u64& m, u64& l, u64& rr) {
    if (r < 0 || r >= HW) { m = 0; l = 0; rr = 0; return; }
    const u64* row = &S[r * SROW];
    m  = row[wcol];
    l  = wcol ? row[wcol - 1] : 0ULL;
    rr = (wcol < 7) ? row[wcol + 1] : 0ULL;
  };

  auto subIter = [&](int sub) {
    u64 am, al, ar, bm, bl, br, cmv, clv, crv;
    u64 nw[4], oldc[4];
    loadRow(r0 - 1, am, al, ar);
    loadRow(r0,     bm, bl, br);
#pragma unroll
    for (int i = 0; i < 4; i++) {
      loadRow(r0 + 1 + i, cmv, clv, crv);
      oldc[i] = bm;
      nw[i] = thin_word(am, al, ar, bm, bl, br, cmv, clv, crv, sub);
      am = bm; al = bl; ar = br;
      bm = cmv; bl = clv; br = crv;
    }
    __syncthreads();
    bool ch = false;
#pragma unroll
    for (int i = 0; i < 4; i++) {
      S[(r0 + i) * SROW + wcol] = nw[i];
      ch |= (nw[i] != oldc[i]);
    }
    if (ch) flag = 1;
    __syncthreads();
  };

  auto thinConverge = [&]() {
    for (int it = 0; it < 2000; ++it) {
      if (tid == 0) flag = 0;
      __syncthreads();
      subIter(0);
      subIter(1);
      int f = flag;
      __syncthreads();
      if (!f) break;
    }
  };

  buildPred();
  thinConverge();
  u64 pr[4];
  u64 spL = 0;
#pragma unroll
  for (int i = 0; i < 4; i++) {
    pr[i] = S[(r0 + i) * SROW + wcol];
    spL += (u64)__popcll(pr[i]);
  }
  __syncthreads();

  buildTrue();
  thinConverge();
  u64 stL = 0, inL = 0;
#pragma unroll
  for (int i = 0; i < 4; i++) {
    u64 tw = S[(r0 + i) * SROW + wcol];
    stL += (u64)__popcll(tw);
    inL += (u64)__popcll(tw & pr[i]);
  }

  for (int o = 32; o; o >>= 1) {
    spL += __shfl_down(spL, o, 64);
    stL += __shfl_down(stL, o, 64);
    inL += __shfl_down(inL, o, 64);
  }
  if (lane == 0) {
    atomicAdd(clSp + b, spL);
    atomicAdd(clSt + b, stL);
    atomicAdd(clInter + b, inL);
  }
}

// ---------------- launch ----------------

extern "C" void kernel_launch(void* const* d_in, const int* in_sizes, int n_in,
                              void* d_out, int out_size, void* d_ws, size_t ws_size,
                              hipStream_t stream) {
  const float* logits = (const float*)d_in[0];
  const int* tr = (const int*)d_in[1];
  float* out = (float*)d_out;
  unsigned char* ws = (unsigned char*)d_ws;

  if (ws_size >= WS_NEED_MASKS) {
    hipLaunchKernelGGL(mask_kernel, dim3(256), dim3(256), 0, stream, logits, tr, ws);
    hipLaunchKernelGGL(fused_kernel, dim3(32 + RED_BLOCKS), dim3(1024), 0, stream,
                       logits, tr, ws);
    hipLaunchKernelGGL(inter_kernel, dim3(NB), dim3(256), 0, stream, ws);
    hipLaunchKernelGGL(finalize_kernel, dim3(1), dim3(512), 0, stream, ws, out, RED_BLOCKS);
  } else {
    hipMemsetAsync(d_ws, 0, 512, stream);
    hipLaunchKernelGGL(loss_reduce_fb_kernel, dim3(FB_BLOCKS), dim3(256), 0, stream,
                       logits, tr, ws);
    hipLaunchKernelGGL(skel_combined_kernel, dim3(NB), dim3(1024), 0, stream,
                       logits, tr, ws);
    hipLaunchKernelGGL(finalize_kernel, dim3(1), dim3(512), 0, stream, ws, out, FB_BLOCKS);
  }
}

// Round 4
// 126.698 us; speedup vs baseline: 1.1673x; 1.1673x over previous
//
#include <hip/hip_runtime.h>
#include <hip/hip_bf16.h>

typedef unsigned long long u64;

#define NB 16
#define HW 512
#define PIX_PER_B (HW * HW)            // 262144
#define NPIX (NB * PIX_PER_B)          // 4194304
#define WORDS_PER_B (PIX_PER_B / 64)   // 4096
#define SROW 9                         // LDS row stride in u64 (8 + 1 pad -> bank-safe)

#define WS_PART_OFF 1024
#define WS_MASK_OFF 32768
#define WS_NEED_MASKS (WS_MASK_OFF + (size_t)2 * NB * WORDS_PER_B * 8)

#define RED_BLOCKS 224                 // reduce blocks inside fused kernel
#define FB_BLOCKS 512                  // fallback loss_reduce blocks
#define MASK_BLOCKS 2048               // 8 blocks/CU -> 32 waves/CU for BW

// ws layout (bytes): [64,192) clInter[16], [192,320) clSp[16], [320,448) clSt[16],
// [448,576) done[16] flags, [1024,...) reduce partials, [32768,...) 32 image regions.

// ---------------- bit-sliced Zhang-Suen helpers ----------------

__device__ __forceinline__ void fa3(u64 a, u64 b, u64 c, u64& s, u64& cy) {
  u64 x = a ^ b;
  s = x ^ c;
  cy = (a & b) | (c & x);
}

__device__ __forceinline__ u64 thin_word(u64 nm, u64 nl, u64 nr,
                                         u64 cm, u64 cl, u64 cr,
                                         u64 sm, u64 sl, u64 sr, int sub) {
  u64 p2 = nm;                          // N
  u64 p3 = (nm >> 1) | (nr << 63);      // NE
  u64 p4 = (cm >> 1) | (cr << 63);      // E
  u64 p5 = (sm >> 1) | (sr << 63);      // SE
  u64 p6 = sm;                          // S
  u64 p7 = (sm << 1) | (sl >> 63);      // SW
  u64 p8 = (cm << 1) | (cl >> 63);      // W
  u64 p9 = (nm << 1) | (nl >> 63);      // NW

  u64 u1, v1, u2, v2, ss, sc, cs, cc;
  fa3(p2, p3, p4, u1, v1);
  fa3(p5, p6, p7, u2, v2);
  u64 u3 = p8 ^ p9, v3 = p8 & p9;
  fa3(u1, u2, u3, ss, sc);
  fa3(v1, v2, v3, cs, cc);
  u64 w  = sc & cs;
  u64 b1 = sc ^ cs;
  u64 b2 = cc ^ w;
  u64 b3 = cc & w;
  u64 cond1 = (sc | cs | cc) & ~(b3 | (b2 & b1 & ss));  // 2 <= B <= 6

  u64 t0 = ~p2 & p3, t1 = ~p3 & p4, t2 = ~p4 & p5, t3 = ~p5 & p6;
  u64 t4 = ~p6 & p7, t5 = ~p7 & p8, t6 = ~p8 & p9, t7 = ~p9 & p2;
  u64 as1, ac1, as2, ac2, Ass, Asc, Acs, Acc;
  fa3(t0, t1, t2, as1, ac1);
  fa3(t3, t4, t5, as2, ac2);
  u64 as3 = t6 ^ t7, ac3 = t6 & t7;
  fa3(as1, as2, as3, Ass, Asc);
  fa3(ac1, ac2, ac3, Acs, Acc);
  u64 cond2 = Ass & ~(Asc | Acs | Acc);  // A == 1

  u64 cond3, cond4;
  if (sub == 0) { cond3 = ~(p2 & p4 & p6); cond4 = ~(p4 & p6 & p8); }
  else          { cond3 = ~(p2 & p4 & p8); cond4 = ~(p2 & p6 & p8); }

  u64 rem = cm & cond1 & cond2 & cond3 & cond4;
  return cm & ~rem;
}

// ---------------- kernel 1: binarization masks (tile-strided ballot) ----------------
// Lane l, element k of a wave handles pixel tile + k*64 + l, so __ballot(cmp_k)
// IS word k of the tile directly — no repacking. 2048 blocks -> 32 waves/CU.

__global__ __launch_bounds__(256) void mask_kernel(
    const float* __restrict__ logits, const int* __restrict__ tr,
    unsigned char* __restrict__ ws) {
  int tid = threadIdx.x, blk = blockIdx.x;
  int lane = tid & 63;
  u64* predM = (u64*)(ws + WS_MASK_OFF);
  u64* trueM = predM + (size_t)NB * WORDS_PER_B;
  if (blk == 0 && tid < 64) ((u64*)(ws + 64))[tid] = 0;  // zero counters+flags [64,576)

  int wv = (blk * 256 + tid) >> 6;       // wave id 0..8191
#pragma unroll
  for (int it = 0; it < 2; ++it) {
    int T = wv * 2 + it;                 // tile of 256 px
    int P = T << 8;
    int b = P >> 18;
    int rbase = (P & (PIX_PER_B - 1)) + lane;
    const float* lp0 = logits + (size_t)b * 2 * PIX_PER_B;
    const float* lp1 = lp0 + PIX_PER_B;
    const int* tp = tr + (size_t)b * PIX_PER_B;
    float l0v[4], l1v[4];
    int tv[4];
#pragma unroll
    for (int k = 0; k < 4; k++) {
      int r = rbase + k * 64;
      l0v[k] = lp0[r];
      l1v[k] = lp1[r];
      tv[k] = tp[r];
    }
    u64 pw[4], twd[4];
#pragma unroll
    for (int k = 0; k < 4; k++) {
      pw[k] = __ballot(l1v[k] > l0v[k]);
      twd[k] = __ballot(tv[k] > 0);
    }
    if (lane == 0) {
#pragma unroll
      for (int k = 0; k < 4; k++) {
        predM[T * 4 + k] = pw[k];
        trueM[T * 4 + k] = twd[k];
      }
    }
  }
}

// ---------------- kernel 2: FUSED. Blocks 0..15 pred-skel, 16..31 true-skel (+inter),
// blocks 32..255 dice/focal reduction. All 256 blocks co-resident -> spin-safe. ----------------

__global__ __launch_bounds__(1024) void fused_kernel(
    const float* __restrict__ logits, const int* __restrict__ tr,
    unsigned char* __restrict__ ws) {
  __shared__ u64 S[HW * SROW];                  // 36 KB
  __shared__ unsigned char dirty[2][130];
  __shared__ int flag;
  __shared__ double red[16][6];

  int tid  = threadIdx.x;
  int lane = tid & 63;

  if (blockIdx.x < 32) {
    // ------------- skeletonization path -------------
    int b    = blockIdx.x;                      // 0..15 pred, 16..31 true
    int img  = b & 15;
    int wcol = tid & 7;
    int s    = tid >> 3;                        // strip 0..127 (4 rows)
    int r0   = s * 4;

    u64* region = (u64*)(ws + WS_MASK_OFF) + (size_t)b * WORDS_PER_B;
    u64* clInter = (u64*)(ws + 64);
    u64* clSp    = (u64*)(ws + 192);
    u64* clSt    = (u64*)(ws + 320);
    u64* done    = (u64*)(ws + 448);

#pragma unroll
    for (int i = 0; i < 4; i++)
      S[(r0 + i) * SROW + wcol] = region[(r0 + i) * 8 + wcol];
    if (tid < 130) {
      unsigned char init = (tid >= 1 && tid <= 128) ? 1 : 0;
      dirty[0][tid] = init;
      dirty[1][tid] = init;
    }
    if (tid == 0) flag = 0;
    __syncthreads();

    auto loadRow = [&](int r, u64& m, u64& l, u64& rr) {
      if (r < 0 || r >= HW) { m = 0; l = 0; rr = 0; return; }
      const u64* row = &S[r * SROW];
      m  = row[wcol];
      l  = wcol ? row[wcol - 1] : 0ULL;
      rr = (wcol < 7) ? row[wcol + 1] : 0ULL;
    };

    auto subIter = [&](int sub, int db, int pairTag) {
      unsigned char* dOut = dirty[db ^ 1];
      bool laneActive = (dirty[0][s] | dirty[0][s + 1] | dirty[0][s + 2] |
                         dirty[1][s] | dirty[1][s + 1] | dirty[1][s + 2]) != 0;
      u64 wmask = __ballot(laneActive);         // whole-wave skip (32-row band)
      bool stripCh = false;
      u64 nw[4];
      bool doit = (wmask != 0);
      if (doit) {
        u64 am, al, ar, bm, bl, br, cmv, clv, crv, oldc[4];
        loadRow(r0 - 1, am, al, ar);
        loadRow(r0,     bm, bl, br);
#pragma unroll
        for (int i = 0; i < 4; i++) {
          loadRow(r0 + 1 + i, cmv, clv, crv);
          oldc[i] = bm;
          nw[i] = thin_word(am, al, ar, bm, bl, br, cmv, clv, crv, sub);
          am = bm; al = bl; ar = br;
          bm = cmv; bl = clv; br = crv;
        }
        bool ch = false;
#pragma unroll
        for (int i = 0; i < 4; i++) ch |= (nw[i] != oldc[i]);
        u64 bal = __ballot(ch);
        stripCh = ((bal >> (lane & 56)) & 0xFFULL) != 0;
      }
      __syncthreads();                          // reads of old state done
      if (doit) {
#pragma unroll
        for (int i = 0; i < 4; i++) S[(r0 + i) * SROW + wcol] = nw[i];
      }
      if ((tid & 7) == 0) {
        dOut[s + 1] = stripCh ? 1 : 0;
        if (stripCh) flag = pairTag;            // benign same-value race
      }
      __syncthreads();                          // writes + dirty + flag visible
    };

    for (int pair = 1; pair <= 2000; ++pair) {
      subIter(0, 0, pair);
      subIter(1, 1, pair);
      if (flag != pair) break;
    }

    u64 own[4];
    u64 cnt = 0;
#pragma unroll
    for (int i = 0; i < 4; i++) {
      own[i] = S[(r0 + i) * SROW + wcol];
      cnt += (u64)__popcll(own[i]);
    }
    for (int o = 32; o; o >>= 1) cnt += __shfl_down(cnt, o, 64);

    if (b < NB) {
      // pred: publish skeleton + done flag
#pragma unroll
      for (int i = 0; i < 4; i++) region[(r0 + i) * 8 + wcol] = own[i];
      if (lane == 0) atomicAdd(clSp + img, cnt);
      __syncthreads();                          // all skeleton stores drained (vmcnt@barrier)
      if (tid == 0) {
        __threadfence();
        __hip_atomic_store(&done[img], 1ULL, __ATOMIC_RELEASE, __HIP_MEMORY_SCOPE_AGENT);
      }
    } else {
      // true: count, then intersect with pred skeleton (read cross-XCD safely)
      if (lane == 0) atomicAdd(clSt + img, cnt);
      if (tid == 0) {
        while (__hip_atomic_load(&done[img], __ATOMIC_ACQUIRE,
                                 __HIP_MEMORY_SCOPE_AGENT) == 0ULL) {
          __builtin_amdgcn_s_sleep(8);
        }
        __threadfence();
      }
      __syncthreads();
      const u64* predRegion = (const u64*)(ws + WS_MASK_OFF) + (size_t)img * WORDS_PER_B;
      u64 inL = 0;
#pragma unroll
      for (int i = 0; i < 4; i++) {
        u64 pw = __hip_atomic_load(&predRegion[(r0 + i) * 8 + wcol],
                                   __ATOMIC_RELAXED, __HIP_MEMORY_SCOPE_AGENT);
        inL += (u64)__popcll(pw & own[i]);
      }
      for (int o = 32; o; o >>= 1) inL += __shfl_down(inL, o, 64);
      if (lane == 0) atomicAdd(clInter + img, inL);
    }

  } else {
    // ------------- dice/focal reduction path -------------
    int rb = blockIdx.x - 32;                   // 0..223
    double a0 = 0, a1 = 0, s0 = 0, s1 = 0, cnt = 0, fo = 0;
    for (int g = rb * 1024 + tid; g < NPIX; g += RED_BLOCKS * 1024) {
      int b = g >> 18;
      int r = g & (PIX_PER_B - 1);
      const float* lp = logits + (size_t)b * 2 * PIX_PER_B + r;
      float l0 = lp[0], l1 = lp[PIX_PER_B];
      int t = tr[g];
      float m = fmaxf(l0, l1);
      float e0 = expf(l0 - m), e1 = expf(l1 - m);
      float ssum = e0 + e1;
      float p0 = e0 / ssum, p1 = e1 / ssum;
      if (t) a1 += (double)p1; else a0 += (double)p0;
      s0 += (double)p0;
      s1 += (double)p1;
      cnt += (double)t;
      float lse = m + logf(ssum);
      float ce = lse - (t ? l1 : l0);
      float pt = t ? p1 : p0;
      float om = 1.0f - pt;
      fo += (double)(0.25f * om * om * ce);
    }
    double v[6] = {a0, a1, s0, s1, cnt, fo};
    int wv = tid >> 6;
#pragma unroll
    for (int j = 0; j < 6; j++) {
      double x = v[j];
      for (int o = 32; o; o >>= 1) x += __shfl_down(x, o, 64);
      if (lane == 0) red[wv][j] = x;
    }
    __syncthreads();
    if (tid < 6) {
      double t6 = 0;
      for (int w = 0; w < 16; w++) t6 += red[w][tid];
      double* part = (double*)(ws + WS_PART_OFF) + (size_t)rb * 6;
      part[tid] = t6;
    }
  }
}

// ---------------- kernel 3: finalize ----------------

__global__ __launch_bounds__(512) void finalize_kernel(unsigned char* __restrict__ ws,
                                                       float* __restrict__ out, int count) {
  int tid = threadIdx.x;
  const double* part = (const double*)(ws + WS_PART_OFF);
  double v[6] = {0, 0, 0, 0, 0, 0};
  if (tid < count) {
#pragma unroll
    for (int j = 0; j < 6; j++) v[j] = part[(size_t)tid * 6 + j];
  }
  __shared__ double red[8][6];
  int lane = tid & 63, wv = tid >> 6;
#pragma unroll
  for (int j = 0; j < 6; j++) {
    double x = v[j];
    for (int o = 32; o; o >>= 1) x += __shfl_down(x, o, 64);
    if (lane == 0) red[wv][j] = x;
  }
  __syncthreads();
  if (tid == 0) {
    double t[6] = {0, 0, 0, 0, 0, 0};
    for (int w = 0; w < 8; w++)
      for (int j = 0; j < 6; j++) t[j] += red[w][j];
    double a0 = t[0], a1 = t[1], s0 = t[2], s1 = t[3], cnt = t[4], fo = t[5];

    const double N = (double)NPIX;
    double cnt0 = N - cnt;
    double card0 = s0 + cnt0, card1 = s1 + cnt;
    double dice = 0.5 * ((2.0 * a0 + 1e-6) / (card0 + 1e-6) +
                         (2.0 * a1 + 1e-6) / (card1 + 1e-6));
    double diceL = 1.0 - dice;
    double focalL = fo / N;

    const u64* clInter = (const u64*)(ws + 64);
    const u64* clSp    = (const u64*)(ws + 192);
    const u64* clSt    = (const u64*)(ws + 320);
    double cs = 0;
    for (int b = 0; b < NB; b++) {
      double inter = (double)clInter[b];
      double den = (double)(clSp[b] + clSt[b]);
      cs += (2.0 * inter + 1e-6) / (den + 1e-6);
    }
    double clL = 1.0 - cs / (double)NB;

    out[0] = (float)(0.7 * clL + 0.1 * diceL + 0.2 * focalL);
  }
}

// ---------------- fallback kernels (ws too small) ----------------

__global__ __launch_bounds__(256) void loss_reduce_fb_kernel(
    const float* __restrict__ logits, const int* __restrict__ tr,
    unsigned char* __restrict__ ws) {
  int tid = threadIdx.x;
  double a0 = 0, a1 = 0, s0 = 0, s1 = 0, cnt = 0, fo = 0;
  const int iters = NPIX / (FB_BLOCKS * 256);
  for (int it = 0; it < iters; ++it) {
    int g = (it * FB_BLOCKS + (int)blockIdx.x) * 256 + tid;
    int b = g >> 18;
    int r = g & (PIX_PER_B - 1);
    const float* lp = logits + (size_t)b * 2 * PIX_PER_B + r;
    float l0 = lp[0], l1 = lp[PIX_PER_B];
    int t = tr[g];
    float m = fmaxf(l0, l1);
    float e0 = expf(l0 - m), e1 = expf(l1 - m);
    float s = e0 + e1;
    float p0 = e0 / s, p1 = e1 / s;
    if (t) a1 += (double)p1; else a0 += (double)p0;
    s0 += (double)p0;
    s1 += (double)p1;
    cnt += (double)t;
    float lse = m + logf(s);
    float ce = lse - (t ? l1 : l0);
    float pt = t ? p1 : p0;
    float om = 1.0f - pt;
    fo += (double)(0.25f * om * om * ce);
  }
  __shared__ double red[4][6];
  double v[6] = {a0, a1, s0, s1, cnt, fo};
  int lane = tid & 63, wv = tid >> 6;
#pragma unroll
  for (int j = 0; j < 6; j++) {
    double x = v[j];
    for (int o = 32; o; o >>= 1) x += __shfl_down(x, o, 64);
    if (lane == 0) red[wv][j] = x;
  }
  __syncthreads();
  if (tid < 6) {
    double* part = (double*)(ws + WS_PART_OFF) + (size_t)blockIdx.x * 6;
    part[tid] = red[0][tid] + red[1][tid] + red[2][tid] + red[3][tid];
  }
}

__global__ __launch_bounds__(1024) void skel_combined_kernel(
    const float* __restrict__ logits, const int* __restrict__ tr,
    unsigned char* __restrict__ ws) {
  __shared__ u64 S[HW * SROW];
  __shared__ int flag;

  int tid  = threadIdx.x;
  int b    = blockIdx.x;
  int wcol = tid & 7;
  int r0   = (tid >> 3) * 4;
  int lane = tid & 63;

  u64* clInter = (u64*)(ws + 64);
  u64* clSp    = (u64*)(ws + 192);
  u64* clSt    = (u64*)(ws + 320);

  auto buildPred = [&]() {
    const float* lp0 = logits + (size_t)b * 2 * PIX_PER_B;
    const float* lp1 = lp0 + PIX_PER_B;
    for (int k = 0; k < PIX_PER_B / 1024; k++) {
      int p = k * 1024 + tid;
      u64 msk = __ballot(lp1[p] > lp0[p]);
      if (lane == 0) { int wi = p >> 6; S[(wi >> 3) * SROW + (wi & 7)] = msk; }
    }
    __syncthreads();
  };
  auto buildTrue = [&]() {
    const int* tp = tr + (size_t)b * PIX_PER_B;
    for (int k = 0; k < PIX_PER_B / 1024; k++) {
      int p = k * 1024 + tid;
      u64 msk = __ballot(tp[p] > 0);
      if (lane == 0) { int wi = p >> 6; S[(wi >> 3) * SROW + (wi & 7)] = msk; }
    }
    __syncthreads();
  };

  auto loadRow = [&](int r, u64& m, u64& l, u64& rr) {
    if (r < 0 || r >= HW) { m = 0; l = 0; rr = 0; return; }
    const u64* row = &S[r * SROW];
    m  = row[wcol];
    l  = wcol ? row[wcol - 1] : 0ULL;
    rr = (wcol < 7) ? row[wcol + 1] : 0ULL;
  };

  auto subIter = [&](int sub) {
    u64 am, al, ar, bm, bl, br, cmv, clv, crv;
    u64 nw[4], oldc[4];
    loadRow(r0 - 1, am, al, ar);
    loadRow(r0,     bm, bl, br);
#pragma unroll
    for (int i = 0; i < 4; i++) {
      loadRow(r0 + 1 + i, cmv, clv, crv);
      oldc[i] = bm;
      nw[i] = thin_word(am, al, ar, bm, bl, br, cmv, clv, crv, sub);
      am = bm; al = bl; ar = br;
      bm = cmv; bl = clv; br = crv;
    }
    __syncthreads();
    bool ch = false;
#pragma unroll
    for (int i = 0; i < 4; i++) {
      S[(r0 + i) * SROW + wcol] = nw[i];
      ch |= (nw[i] != oldc[i]);
    }
    if (ch) flag = 1;
    __syncthreads();
  };

  auto thinConverge = [&]() {
    for (int it = 0; it < 2000; ++it) {
      if (tid == 0) flag = 0;
      __syncthreads();
      subIter(0);
      subIter(1);
      int f = flag;
      __syncthreads();
      if (!f) break;
    }
  };

  buildPred();
  thinConverge();
  u64 pr[4];
  u64 spL = 0;
#pragma unroll
  for (int i = 0; i < 4; i++) {
    pr[i] = S[(r0 + i) * SROW + wcol];
    spL += (u64)__popcll(pr[i]);
  }
  __syncthreads();

  buildTrue();
  thinConverge();
  u64 stL = 0, inL = 0;
#pragma unroll
  for (int i = 0; i < 4; i++) {
    u64 tw = S[(r0 + i) * SROW + wcol];
    stL += (u64)__popcll(tw);
    inL += (u64)__popcll(tw & pr[i]);
  }

  for (int o = 32; o; o >>= 1) {
    spL += __shfl_down(spL, o, 64);
    stL += __shfl_down(stL, o, 64);
    inL += __shfl_down(inL, o, 64);
  }
  if (lane == 0) {
    atomicAdd(clSp + b, spL);
    atomicAdd(clSt + b, stL);
    atomicAdd(clInter + b, inL);
  }
}

// ---------------- launch ----------------

extern "C" void kernel_launch(void* const* d_in, const int* in_sizes, int n_in,
                              void* d_out, int out_size, void* d_ws, size_t ws_size,
                              hipStream_t stream) {
  const float* logits = (const float*)d_in[0];
  const int* tr = (const int*)d_in[1];
  float* out = (float*)d_out;
  unsigned char* ws = (unsigned char*)d_ws;

  if (ws_size >= WS_NEED_MASKS) {
    hipLaunchKernelGGL(mask_kernel, dim3(MASK_BLOCKS), dim3(256), 0, stream,
                       logits, tr, ws);
    hipLaunchKernelGGL(fused_kernel, dim3(32 + RED_BLOCKS), dim3(1024), 0, stream,
                       logits, tr, ws);
    hipLaunchKernelGGL(finalize_kernel, dim3(1), dim3(512), 0, stream, ws, out, RED_BLOCKS);
  } else {
    hipMemsetAsync(d_ws, 0, 512, stream);
    hipLaunchKernelGGL(loss_reduce_fb_kernel, dim3(FB_BLOCKS), dim3(256), 0, stream,
                       logits, tr, ws);
    hipLaunchKernelGGL(skel_combined_kernel, dim3(NB), dim3(1024), 0, stream,
                       logits, tr, ws);
    hipLaunchKernelGGL(finalize_kernel, dim3(1), dim3(512), 0, stream, ws, out, FB_BLOCKS);
  }
}